// Round 9
// baseline (26.315 us; speedup 1.0000x reference)
//
#include <hip/hip_runtime.h>

// b=4, f=6, n_slots=7, n_buffer=8, h=w=128, 3 channels. bf=24.
constexpr int NB  = 8;
constexpr int NS  = 7;
constexpr int NCH = 3;
constexpr int HW  = 128 * 128;    // 16384
constexpr int BF  = 24;
constexpr int BLOCK = 256;
constexpr int BLOCKS_PER_BF = HW / BLOCK;        // 64, 1 px/thread, all 8 buffers
constexpr int NPART = BF * BLOCKS_PER_BF;        // 1536 blocks / partials
constexpr float INV_HW = 1.0f / (float)HW;
constexpr float SCALE  = 20.0f / (4.0f * 6.0f * 7.0f * 8.0f);
constexpr float LOG_CLAMP = -100.0f;

__global__ __launch_bounds__(BLOCK, 6)   // VGPR cap 85: 49 scalar loads fit, 24 waves/CU
void em_loss_kernel(const float* __restrict__ seg,
                    const float* __restrict__ masks,
                    const float* __restrict__ rec,
                    const float* __restrict__ rtgt,
                    const float* __restrict__ mvis,
                    const float* __restrict__ ai,
                    float* __restrict__ part) {
    const int bid   = blockIdx.x;
    const int bf    = bid >> 6;                  // / BLOCKS_PER_BF
    const int chunk = bid & 63;
    const int tid   = threadIdx.x;
    const int hw    = chunk * BLOCK + tid;       // 1 px/thread

    __shared__ float ai_s[NS][NB];
    __shared__ float A_s[NB];
    if (tid < NS * NB)
        ((float*)ai_s)[tid] = ai[bf * NS * NB + tid];
    __syncthreads();
    if (tid < NB) {
        float a = 0.f;
        #pragma unroll
        for (int s = 0; s < NS; ++s) a += ai_s[s][tid];
        A_s[tid] = a;
    }
    __syncthreads();

    const float* segp = seg  + (size_t)bf * NB * HW        + hw;
    const float* mp   = masks + (size_t)bf * NS * HW       + hw;
    const float* rp   = rec  + (size_t)bf * NB * NCH * HW  + hw;
    const float* tp   = rtgt + (size_t)bf * NCH * HW       + hw;
    const float* vp   = mvis + (size_t)bf * NS * HW        + hw;

    // ---- Issue ALL 49 scalar loads up front; keep results live. ----
    float sv[NB];
    #pragma unroll
    for (int c = 0; c < NB; ++c) sv[c] = segp[c * HW];

    float rr[NB][NCH];
    #pragma unroll
    for (int c = 0; c < NB; ++c)
        #pragma unroll
        for (int ch = 0; ch < NCH; ++ch)
            rr[c][ch] = rp[(c * NCH + ch) * HW];

    float mvv[NS], vvv[NS];
    #pragma unroll
    for (int s = 0; s < NS; ++s) mvv[s] = mp[s * HW];
    #pragma unroll
    for (int s = 0; s < NS; ++s) vvv[s] = vp[s * HW];

    float t[NCH];
    #pragma unroll
    for (int ch = 0; ch < NCH; ++ch) t[ch] = tp[ch * HW];

    // ---- Compute ----
    float mb[NS], vb[NS];
    #pragma unroll
    for (int s = 0; s < NS; ++s) {
        mb[s] = (mvv[s] > 0.5f) ? 1.f : 0.f;
        vb[s] = (vvv[s] > 0.5f) ? 1.f : 0.f;
    }

    float acc = 0.f;
    #pragma unroll
    for (int c = 0; c < NB; ++c) {
        float s  = sv[c];
        float lp = fmaxf(__logf(s), LOG_CLAMP);
        float l1 = fmaxf(__logf(1.0f - s), LOG_CLAMP);
        float d0 = rr[c][0] - t[0];
        float d1 = rr[c][1] - t[1];
        float d2 = rr[c][2] - t[2];
        float D  = d0 * d0 + d1 * d1 + d2 * d2;
        float U = 0.f, V = 0.f;
        #pragma unroll
        for (int s7 = 0; s7 < NS; ++s7) {
            float a = ai_s[s7][c];
            U = fmaf(mb[s7], a, U);
            V = fmaf(vb[s7], a, V);
        }
        acc += -(A_s[c] * l1 + U * (lp - l1)) * INV_HW + 0.1f * V * D;
    }

    // wave reduce, cross-wave via LDS, one plain store per block (no atomics)
    #pragma unroll
    for (int off = 32; off; off >>= 1) acc += __shfl_down(acc, off, 64);
    __shared__ float wsum[BLOCK / 64];
    const int wid  = tid >> 6;
    const int lane = tid & 63;
    if (lane == 0) wsum[wid] = acc;
    __syncthreads();
    if (tid == 0)
        part[blockIdx.x] = wsum[0] + wsum[1] + wsum[2] + wsum[3];
}

__global__ __launch_bounds__(BLOCK)
void reduce_kernel(const float* __restrict__ part, float* __restrict__ out) {
    const int tid = threadIdx.x;
    float a = 0.f;
    #pragma unroll
    for (int i = 0; i < NPART / BLOCK; ++i)      // 6 each
        a += part[i * BLOCK + tid];
    #pragma unroll
    for (int off = 32; off; off >>= 1) a += __shfl_down(a, off, 64);
    __shared__ float fsum[BLOCK / 64];
    if ((tid & 63) == 0) fsum[tid >> 6] = a;
    __syncthreads();
    if (tid == 0) out[0] = (fsum[0] + fsum[1] + fsum[2] + fsum[3]) * SCALE;
}

extern "C" void kernel_launch(void* const* d_in, const int* in_sizes, int n_in,
                              void* d_out, int out_size, void* d_ws, size_t ws_size,
                              hipStream_t stream) {
    const float* seg   = (const float*)d_in[0];  // (4,6,8,128,128)
    const float* masks = (const float*)d_in[1];  // (4,6,7,128,128)
    const float* rec   = (const float*)d_in[2];  // (4,6,8,3,128,128)
    const float* rtgt  = (const float*)d_in[3];  // (4,6,3,128,128)
    const float* mvis  = (const float*)d_in[4];  // (4,6,7,128,128)
    const float* ai    = (const float*)d_in[5];  // (4,6,7,8)
    float* out  = (float*)d_out;
    float* part = (float*)d_ws;                  // 1536 floats, fully overwritten each call

    em_loss_kernel<<<NPART, BLOCK, 0, stream>>>(seg, masks, rec, rtgt, mvis, ai, part);
    reduce_kernel<<<1, BLOCK, 0, stream>>>(part, out);
}